// Round 2
// baseline (552.653 us; speedup 1.0000x reference)
//
#include <hip/hip_runtime.h>

typedef unsigned short u16;
typedef unsigned int   u32;
typedef __attribute__((ext_vector_type(8))) short bf16x8;   // 8 bf16 in 4 VGPRs
typedef __attribute__((ext_vector_type(4))) float f32x4;

__device__ inline float bf2f(u16 u) { return __uint_as_float(((u32)u) << 16); }
__device__ inline u16 f2bf(float f) {
  u32 u = __float_as_uint(f);
  return (u16)((u + 0x7FFFu + ((u >> 16) & 1u)) >> 16);   // RNE
}

__device__ inline void gld_lds16(const u16* g, u16* l) {
  __builtin_amdgcn_global_load_lds((const __attribute__((address_space(1))) void*)g,
                                   (__attribute__((address_space(3))) void*)l,
                                   16, 0, 0);
}

// ---- f32 -> bf16 conversion of the 5 GEMM operand tensors (vec4) ----
// hs 2M | w_in 4M | w_x 196608 | w_dt 131072 | w_out 2M  elements
__global__ __launch_bounds__(256) void cvt_k(
    const float* __restrict__ hs, const float* __restrict__ w_in,
    const float* __restrict__ w_x, const float* __restrict__ w_dt,
    const float* __restrict__ w_out,
    u16* __restrict__ hs_b, u16* __restrict__ w_in_b, u16* __restrict__ w_x_b,
    u16* __restrict__ w_dt_b, u16* __restrict__ w_out_b)
{
  u32 v = blockIdx.x * 256 + threadIdx.x;   // vec4 index, total 2179072
  const float* s; u16* d; u32 loc;
  if      (v < 524288u)  { s = hs;    d = hs_b;    loc = v; }
  else if (v < 1572864u) { s = w_in;  d = w_in_b;  loc = v - 524288u; }
  else if (v < 1622016u) { s = w_x;   d = w_x_b;   loc = v - 1572864u; }
  else if (v < 1654784u) { s = w_dt;  d = w_dt_b;  loc = v - 1622016u; }
  else                   { s = w_out; d = w_out_b; loc = v - 1654784u; }
  float4 f = ((const float4*)s)[loc];
  ushort4 o;
  o.x = f2bf(f.x); o.y = f2bf(f.y); o.z = f2bf(f.z); o.w = f2bf(f.w);
  ((ushort4*)d)[loc] = o;
}

// C = A (MxK bf16, lda) * B^T (B NxK bf16 row-major, ldb), 128x128 tile, BK=32.
// EPI==0: store bf16. EPI==1: store f32 softplus(acc + bias[col]). EPI==2: store f32.
template <int EPI>
__global__ __launch_bounds__(256) void gemm_bt(
    const u16* __restrict__ A, int lda,
    const u16* __restrict__ B, int ldb,
    void* __restrict__ C, int ldc,
    int M, int N, int K,
    const float* __restrict__ bias)
{
  __shared__ u16 sA[128 * 32];
  __shared__ u16 sB[128 * 32];
  const int tid  = threadIdx.x;
  const int wave = tid >> 6, lane = tid & 63;
  const int row0 = blockIdx.x * 128, col0 = blockIdx.y * 128;
  const int r  = lane >> 2, c8 = (lane & 3) * 8;
  const int wm = (wave >> 1) * 64, wn = (wave & 1) * 64;
  const int tm = lane & 15, quad = lane >> 4;

  f32x4 acc[4][4];
#pragma unroll
  for (int i = 0; i < 4; ++i)
#pragma unroll
    for (int j = 0; j < 4; ++j) acc[i][j] = f32x4{0.f, 0.f, 0.f, 0.f};

  for (int k0 = 0; k0 < K; k0 += 32) {
    for (int s = wave; s < 8; s += 4) {
      const u16* ga = A + (size_t)(row0 + s * 16 + r) * lda + (k0 + c8);
      gld_lds16(ga, &sA[s * 512 + lane * 8]);
      int br = col0 + s * 16 + r; br = br < N ? br : N - 1;
      const u16* gb = B + (size_t)br * ldb + (k0 + c8);
      gld_lds16(gb, &sB[s * 512 + lane * 8]);
    }
    __syncthreads();
    bf16x8 af[4], bfv[4];
#pragma unroll
    for (int i = 0; i < 4; ++i) af[i]  = *(const bf16x8*)&sA[(wm + i * 16 + tm) * 32 + quad * 8];
#pragma unroll
    for (int j = 0; j < 4; ++j) bfv[j] = *(const bf16x8*)&sB[(wn + j * 16 + tm) * 32 + quad * 8];
#pragma unroll
    for (int i = 0; i < 4; ++i)
#pragma unroll
      for (int j = 0; j < 4; ++j)
        acc[i][j] = __builtin_amdgcn_mfma_f32_16x16x32_bf16(af[i], bfv[j], acc[i][j], 0, 0, 0);
    __syncthreads();
  }

#pragma unroll
  for (int j = 0; j < 4; ++j) {
    int col = col0 + wn + j * 16 + tm;
    if (col >= N) continue;
#pragma unroll
    for (int i = 0; i < 4; ++i) {
      int rb = row0 + wm + i * 16 + quad * 4;
      f32x4 v = acc[i][j];
#pragma unroll
      for (int t = 0; t < 4; ++t) {
        float f = v[t];
        size_t idx = (size_t)(rb + t) * ldc + col;
        if (EPI == 1) {
          f += bias[col];
          f = (f > 20.f) ? f : log1pf(__expf(f));
          ((float*)C)[idx] = f;
        } else if (EPI == 2) {
          ((float*)C)[idx] = f;
        } else {
          ((u16*)C)[idx] = f2bf(f);
        }
      }
    }
  }
}

// depthwise causal conv (K=4) + bias + silu. xz: (B*L) x 4096 bf16, x = cols 0..2047
__global__ __launch_bounds__(256) void conv_silu_k(
    const u16* __restrict__ xz, const float* __restrict__ cw,
    const float* __restrict__ cb, u16* __restrict__ xc)
{
  int gid = blockIdx.x * 256 + threadIdx.x;
  int d = gid & 2047;
  int row = gid >> 11;        // b*1024 + l
  int l = row & 1023;
  float acc = cb[d];
#pragma unroll
  for (int k = 0; k < 4; ++k) {
    int ll = l - 3 + k;
    if (ll >= 0)
      acc += bf2f(xz[(size_t)(row - 3 + k) * 4096 + d]) * cw[d * 4 + k];
  }
  float s = acc / (1.f + __expf(-acc));
  xc[(size_t)row * 2048 + d] = f2bf(s);
}

// selective scan: block = 16 channels x 16 state-lanes, grid (128, B).
// xcy: x_conv input, y written in-place (same rows, same block, after barrier).
__global__ __launch_bounds__(256) void scan_k(
    const float* __restrict__ dtf,   // (B*L, 2048) f32 post-softplus
    const u16* __restrict__ xdbl,    // (B*L, 96) bf16: [dt_r|Bm|Cm]
    u16* xcy,                        // (B*L, 2048) bf16 in/out
    const u16* __restrict__ xz,      // (B*L, 4096) bf16, z = cols 2048..4095
    const float* __restrict__ A_log, // (2048, 16) f32
    const float* __restrict__ Dw)    // (2048,) f32
{
  const int L = 1024, DI = 2048, CH = 64;
  int b = blockIdx.y;
  int d0 = blockIdx.x * 16;
  int tid = threadIdx.x;
  int g = tid >> 4, n = tid & 15;
  int d = d0 + g;
  float cA = -__expf(A_log[d * 16 + n]);
  float Dd = Dw[d];

  __shared__ float dt_s[16][64];
  __shared__ float x_s[16][64];
  __shared__ float z_s[16][64];
  __shared__ float B_s[64][16];
  __shared__ float C_s[64][16];
  __shared__ u16   y_s[16][64];

  float h = 0.f;
  const size_t rowbase = (size_t)b * L;

  for (int c = 0; c < L / CH; ++c) {
    int lc = c * CH;
    {
      int dd = tid & 15, l4 = tid >> 4;
#pragma unroll
      for (int ll = l4; ll < CH; ll += 16) {
        size_t row = rowbase + lc + ll;
        dt_s[dd][ll] = dtf[row * DI + d0 + dd];
        x_s[dd][ll]  = bf2f(xcy[row * DI + d0 + dd]);
        z_s[dd][ll]  = bf2f(xz[row * 4096 + 2048 + d0 + dd]);
        B_s[ll][dd]  = bf2f(xdbl[row * 96 + 64 + dd]);
        C_s[ll][dd]  = bf2f(xdbl[row * 96 + 80 + dd]);
      }
    }
    __syncthreads();
#pragma unroll 4
    for (int ll = 0; ll < CH; ++ll) {
      float dt = dt_s[g][ll];
      float xv = x_s[g][ll];
      float dA = __expf(dt * cA);
      h = fmaf(dA, h, dt * xv * B_s[ll][n]);
      float p = h * C_s[ll][n];
      p += __shfl_xor(p, 1, 16);
      p += __shfl_xor(p, 2, 16);
      p += __shfl_xor(p, 4, 16);
      p += __shfl_xor(p, 8, 16);
      if (n == 0) {
        float zv = z_s[g][ll];
        float sig = 1.f / (1.f + __expf(-zv));
        float yv = (p + xv * Dd) * (zv * sig);
        y_s[g][ll] = f2bf(yv);
      }
    }
    __syncthreads();
    {
      int dd = tid & 15, l4 = tid >> 4;
#pragma unroll
      for (int ll = l4; ll < CH; ll += 16)
        xcy[(rowbase + lc + ll) * DI + d0 + dd] = y_s[dd][ll];
    }
    __syncthreads();
  }
}

extern "C" void kernel_launch(void* const* d_in, const int* in_sizes, int n_in,
                              void* d_out, int out_size, void* d_ws, size_t ws_size,
                              hipStream_t stream)
{
  const float* hs    = (const float*)d_in[0];   // (2,1024,1024)
  const float* w_in  = (const float*)d_in[1];   // (4096,1024)
  const float* cw    = (const float*)d_in[2];   // (2048,1,4)
  const float* cb    = (const float*)d_in[3];   // (2048,)
  const float* w_x   = (const float*)d_in[4];   // (96,2048)
  const float* w_dt  = (const float*)d_in[5];   // (2048,64)
  const float* b_dt  = (const float*)d_in[6];   // (2048,)
  const float* A_log = (const float*)d_in[7];   // (2048,16)
  const float* Dw    = (const float*)d_in[8];   // (2048,)
  const float* w_out = (const float*)d_in[9];   // (1024,2048)

  char* p = (char*)d_ws;
  u16*   hs_b   = (u16*)p; p += (size_t)2097152 * 2;       // 4 MB
  u16*   w_in_b = (u16*)p; p += (size_t)4194304 * 2;       // 8 MB
  u16*   w_x_b  = (u16*)p; p += (size_t)196608 * 2;        // 384 KB
  u16*   w_dt_b = (u16*)p; p += (size_t)131072 * 2;        // 256 KB
  u16*   w_out_b= (u16*)p; p += (size_t)2097152 * 2;       // 4 MB
  u16*   xz     = (u16*)p; p += (size_t)2048 * 4096 * 2;   // 16 MB
  u16*   xc     = (u16*)p; p += (size_t)2048 * 2048 * 2;   // 8 MB (also y, in-place)
  u16*   xdbl   = (u16*)p; p += (size_t)2048 * 96 * 2;     // 384 KB
  float* dtf    = (float*)p;                               // 16 MB  (~57 MB total)
  float* out    = (float*)d_out;

  // convert f32 -> bf16 GEMM operands
  cvt_k<<<8512, 256, 0, stream>>>(hs, w_in, w_x, w_dt, w_out,
                                  hs_b, w_in_b, w_x_b, w_dt_b, w_out_b);
  // xz = hs @ in_proj_w^T            (2048 x 4096, K=1024)
  gemm_bt<0><<<dim3(16, 32), 256, 0, stream>>>(hs_b, 1024, w_in_b, 1024, xz, 4096, 2048, 4096, 1024, nullptr);
  // x = silu(causal_conv(x) + b)
  conv_silu_k<<<16384, 256, 0, stream>>>(xz, cw, cb, xc);
  // x_dbl = x @ x_proj_w^T           (2048 x 96, K=2048)
  gemm_bt<0><<<dim3(16, 1), 256, 0, stream>>>(xc, 2048, w_x_b, 2048, xdbl, 96, 2048, 96, 2048, nullptr);
  // dt = softplus(x_dbl[:, :64] @ dt_proj_w^T + b)   (2048 x 2048, K=64)
  gemm_bt<1><<<dim3(16, 16), 256, 0, stream>>>(xdbl, 96, w_dt_b, 64, dtf, 2048, 2048, 2048, 64, b_dt);
  // selective scan + gating (y overwrites xc in place)
  scan_k<<<dim3(128, 2), 256, 0, stream>>>(dtf, xdbl, xc, xz, A_log, Dw);
  // out = y @ out_proj_w^T           (2048 x 1024, K=2048)
  gemm_bt<2><<<dim3(16, 8), 256, 0, stream>>>(xc, 2048, w_out_b, 2048, out, 1024, 2048, 1024, 2048, nullptr);
}

// Round 7
// 298.975 us; speedup vs baseline: 1.8485x; 1.8485x over previous
//
#include <hip/hip_runtime.h>

typedef unsigned short u16;
typedef unsigned int   u32;
typedef __attribute__((ext_vector_type(8))) short bf16x8;   // 8 bf16 in 4 VGPRs
typedef __attribute__((ext_vector_type(4))) float f32x4;

__device__ inline float bf2f(u16 u) { return __uint_as_float(((u32)u) << 16); }
__device__ inline u16 f2bf(float f) {
  u32 u = __float_as_uint(f);
  return (u16)((u + 0x7FFFu + ((u >> 16) & 1u)) >> 16);   // RNE
}

__device__ inline void gld_lds16(const u16* g, u16* l) {
  __builtin_amdgcn_global_load_lds((const __attribute__((address_space(1))) void*)g,
                                   (__attribute__((address_space(3))) void*)l,
                                   16, 0, 0);
}

// ---- f32 -> bf16 conversion of the 5 GEMM operand tensors (vec4) ----
__global__ __launch_bounds__(256) void cvt_k(
    const float* __restrict__ hs, const float* __restrict__ w_in,
    const float* __restrict__ w_x, const float* __restrict__ w_dt,
    const float* __restrict__ w_out,
    u16* __restrict__ hs_b, u16* __restrict__ w_in_b, u16* __restrict__ w_x_b,
    u16* __restrict__ w_dt_b, u16* __restrict__ w_out_b)
{
  u32 v = blockIdx.x * 256 + threadIdx.x;   // vec4 index, total 2179072
  const float* s; u16* d; u32 loc;
  if      (v < 524288u)  { s = hs;    d = hs_b;    loc = v; }
  else if (v < 1572864u) { s = w_in;  d = w_in_b;  loc = v - 524288u; }
  else if (v < 1622016u) { s = w_x;   d = w_x_b;   loc = v - 1572864u; }
  else if (v < 1654784u) { s = w_dt;  d = w_dt_b;  loc = v - 1622016u; }
  else                   { s = w_out; d = w_out_b; loc = v - 1654784u; }
  float4 f = ((const float4*)s)[loc];
  ushort4 o;
  o.x = f2bf(f.x); o.y = f2bf(f.y); o.z = f2bf(f.z); o.w = f2bf(f.w);
  ((ushort4*)d)[loc] = o;
}

// C = A (MxK bf16, lda) * B^T (B NxK bf16 row-major, ldb), 128x128 tile, BK=32.
// EPI==0: store bf16. EPI==1: store f32 softplus(acc + bias[col]). EPI==2: store f32.
template <int EPI>
__global__ __launch_bounds__(256) void gemm_bt(
    const u16* __restrict__ A, int lda,
    const u16* __restrict__ B, int ldb,
    void* __restrict__ C, int ldc,
    int M, int N, int K,
    const float* __restrict__ bias)
{
  __shared__ u16 sA[128 * 32];
  __shared__ u16 sB[128 * 32];
  const int tid  = threadIdx.x;
  const int wave = tid >> 6, lane = tid & 63;
  const int row0 = blockIdx.x * 128, col0 = blockIdx.y * 128;
  const int r  = lane >> 2, c8 = (lane & 3) * 8;
  const int wm = (wave >> 1) * 64, wn = (wave & 1) * 64;
  const int tm = lane & 15, quad = lane >> 4;

  f32x4 acc[4][4];
#pragma unroll
  for (int i = 0; i < 4; ++i)
#pragma unroll
    for (int j = 0; j < 4; ++j) acc[i][j] = f32x4{0.f, 0.f, 0.f, 0.f};

  for (int k0 = 0; k0 < K; k0 += 32) {
    for (int s = wave; s < 8; s += 4) {
      const u16* ga = A + (size_t)(row0 + s * 16 + r) * lda + (k0 + c8);
      gld_lds16(ga, &sA[s * 512 + lane * 8]);
      int br = col0 + s * 16 + r; br = br < N ? br : N - 1;
      const u16* gb = B + (size_t)br * ldb + (k0 + c8);
      gld_lds16(gb, &sB[s * 512 + lane * 8]);
    }
    __syncthreads();
    bf16x8 af[4], bfv[4];
#pragma unroll
    for (int i = 0; i < 4; ++i) af[i]  = *(const bf16x8*)&sA[(wm + i * 16 + tm) * 32 + quad * 8];
#pragma unroll
    for (int j = 0; j < 4; ++j) bfv[j] = *(const bf16x8*)&sB[(wn + j * 16 + tm) * 32 + quad * 8];
#pragma unroll
    for (int i = 0; i < 4; ++i)
#pragma unroll
      for (int j = 0; j < 4; ++j)
        acc[i][j] = __builtin_amdgcn_mfma_f32_16x16x32_bf16(af[i], bfv[j], acc[i][j], 0, 0, 0);
    __syncthreads();
  }

#pragma unroll
  for (int j = 0; j < 4; ++j) {
    int col = col0 + wn + j * 16 + tm;
    if (col >= N) continue;
#pragma unroll
    for (int i = 0; i < 4; ++i) {
      int rb = row0 + wm + i * 16 + quad * 4;
      f32x4 v = acc[i][j];
#pragma unroll
      for (int t = 0; t < 4; ++t) {
        float f = v[t];
        size_t idx = (size_t)(rb + t) * ldc + col;
        if (EPI == 1) {
          f += bias[col];
          f = (f > 20.f) ? f : log1pf(__expf(f));
          ((float*)C)[idx] = f;
        } else if (EPI == 2) {
          ((float*)C)[idx] = f;
        } else {
          ((u16*)C)[idx] = f2bf(f);
        }
      }
    }
  }
}

// depthwise causal conv (K=4) + bias + silu. xz: (B*L) x 4096 bf16, x = cols 0..2047
__global__ __launch_bounds__(256) void conv_silu_k(
    const u16* __restrict__ xz, const float* __restrict__ cw,
    const float* __restrict__ cb, u16* __restrict__ xc)
{
  int gid = blockIdx.x * 256 + threadIdx.x;
  int d = gid & 2047;
  int row = gid >> 11;        // b*1024 + l
  int l = row & 1023;
  float acc = cb[d];
#pragma unroll
  for (int k = 0; k < 4; ++k) {
    int ll = l - 3 + k;
    if (ll >= 0)
      acc += bf2f(xz[(size_t)(row - 3 + k) * 4096 + d]) * cw[d * 4 + k];
  }
  float s = acc / (1.f + __expf(-acc));
  xc[(size_t)row * 2048 + d] = f2bf(s);
}

// ===== segmented selective scan, S=32 segments of T=32, thread = (b, d, seg) =====
#define SSEG 32
#define TSEG 32

// pass 1: local scan with h0=0; emit h_end per (s,b,d,n) and sum(dt) per (s,b,d)
__global__ __launch_bounds__(256) void scan1_k(
    const float* __restrict__ dtf,   // (B*L, 2048) f32 post-softplus
    const u16* __restrict__ xdbl,    // (B*L, 96) bf16: [dt_r|Bm|Cm]
    const u16* __restrict__ xc,      // (B*L, 2048) bf16
    const float* __restrict__ A_log, // (2048,16) f32
    float* __restrict__ hseg,        // (S,B,2048,16) h_end out
    float* __restrict__ sdt_o)       // (S,B,2048)   sum(dt) out
{
  const int L = 1024, DI = 2048;
  int d = blockIdx.x * 256 + threadIdx.x;
  int b = blockIdx.y, s = blockIdx.z;
  float cA[16], h[16];
#pragma unroll
  for (int n = 0; n < 16; ++n) { cA[n] = -__expf(A_log[d * 16 + n]); h[n] = 0.f; }
  float sdt = 0.f;
  size_t row = (size_t)b * L + s * TSEG;
  const float* pdt = dtf + row * DI + d;
  const u16*   px  = xc  + row * DI + d;
  const u16*   pB  = xdbl + row * 96 + 64;
  for (int t = 0; t < TSEG; ++t) {
    float dt = *pdt;
    float xv = bf2f(*px);
    bf16x8 Bv0 = *(const bf16x8*)(pB);
    bf16x8 Bv1 = *(const bf16x8*)(pB + 8);
    float dBu = dt * xv;
    sdt += dt;
#pragma unroll
    for (int n = 0; n < 16; ++n) {
      float dA = __expf(dt * cA[n]);
      float Bn = bf2f((u16)(n < 8 ? Bv0[n] : Bv1[n - 8]));
      h[n] = fmaf(dA, h[n], dBu * Bn);
    }
    pdt += DI; px += DI; pB += 96;
  }
  size_t o = (((size_t)s * 2 + b) * 2048 + d) * 16;
#pragma unroll
  for (int n = 0; n < 16; ++n) hseg[o + n] = h[n];
  sdt_o[((size_t)s * 2 + b) * 2048 + d] = sdt;
}

// pass 2: sequential combine over segments; hseg: h_end in -> h_start out (in place)
__global__ __launch_bounds__(256) void combine_k(
    float* hseg, const float* __restrict__ sdt,
    const float* __restrict__ A_log)
{
  int gid = blockIdx.x * 256 + threadIdx.x;   // b*32768 + d*16 + n, 65536 total
  int b = gid >> 15, d = (gid >> 4) & 2047, n = gid & 15;
  float cA = -__expf(A_log[d * 16 + n]);
  float carry = 0.f;
  for (int s = 0; s < SSEG; ++s) {
    size_t o = (size_t)s * 65536 + gid;
    float he = hseg[o];
    float P = __expf(cA * sdt[(size_t)s * 4096 + b * 2048 + d]);
    hseg[o] = carry;                 // becomes h_start
    carry = fmaf(P, carry, he);
  }
}

// pass 3: rescan with true h_start; fuse y = C.h + x*D, gate with silu(z); y -> xcy in place
__global__ __launch_bounds__(256) void scan3_k(
    const float* __restrict__ dtf,
    const u16* __restrict__ xdbl,
    u16* xcy,                        // x_conv in, y out (same element, same iteration)
    const u16* __restrict__ xz,      // z = cols 2048..4095, ROW STRIDE 4096
    const float* __restrict__ A_log,
    const float* __restrict__ Dw,
    const float* __restrict__ hstart)
{
  const int L = 1024, DI = 2048;
  int d = blockIdx.x * 256 + threadIdx.x;
  int b = blockIdx.y, s = blockIdx.z;
  float cA[16], h[16];
  size_t ho = (((size_t)s * 2 + b) * 2048 + d) * 16;
#pragma unroll
  for (int n = 0; n < 16; ++n) { cA[n] = -__expf(A_log[d * 16 + n]); h[n] = hstart[ho + n]; }
  float Dd = Dw[d];
  size_t row = (size_t)b * L + s * TSEG;
  const float* pdt = dtf + row * DI + d;
  u16*         px  = xcy + row * DI + d;
  const u16*   pz  = xz  + row * 4096 + 2048 + d;
  const u16*   pBC = xdbl + row * 96 + 64;
  for (int t = 0; t < TSEG; ++t) {
    float dt = *pdt;
    float xv = bf2f(*px);
    float zv = bf2f(*pz);
    bf16x8 Bv0 = *(const bf16x8*)(pBC);
    bf16x8 Bv1 = *(const bf16x8*)(pBC + 8);
    bf16x8 Cv0 = *(const bf16x8*)(pBC + 16);
    bf16x8 Cv1 = *(const bf16x8*)(pBC + 24);
    float dBu = dt * xv;
    float y = xv * Dd;
#pragma unroll
    for (int n = 0; n < 16; ++n) {
      float dA = __expf(dt * cA[n]);
      float Bn = bf2f((u16)(n < 8 ? Bv0[n] : Bv1[n - 8]));
      float Cn = bf2f((u16)(n < 8 ? Cv0[n] : Cv1[n - 8]));
      h[n] = fmaf(dA, h[n], dBu * Bn);
      y = fmaf(h[n], Cn, y);
    }
    float sig = 1.f / (1.f + __expf(-zv));
    *px = f2bf(y * (zv * sig));
    pdt += DI; px += DI; pz += 4096; pBC += 96;   // BUGFIX: xz row stride is 4096 (was += DI)
  }
}

extern "C" void kernel_launch(void* const* d_in, const int* in_sizes, int n_in,
                              void* d_out, int out_size, void* d_ws, size_t ws_size,
                              hipStream_t stream)
{
  const float* hs    = (const float*)d_in[0];   // (2,1024,1024)
  const float* w_in  = (const float*)d_in[1];   // (4096,1024)
  const float* cw    = (const float*)d_in[2];   // (2048,1,4)
  const float* cb    = (const float*)d_in[3];   // (2048,)
  const float* w_x   = (const float*)d_in[4];   // (96,2048)
  const float* w_dt  = (const float*)d_in[5];   // (2048,64)
  const float* b_dt  = (const float*)d_in[6];   // (2048,)
  const float* A_log = (const float*)d_in[7];   // (2048,16)
  const float* Dw    = (const float*)d_in[8];   // (2048,)
  const float* w_out = (const float*)d_in[9];   // (1024,2048)

  // Workspace: 59,768,832 bytes total. Region A (first 12 MB) is time-shared:
  //   phase 1 (cvt, gemm1):  hs_b (4 MB) + w_in_b (8 MB)
  //   phase 2 (scan1/2/3):   hseg (8 MB) + sdt (0.5 MB)
  // gemm1 completes before scan1 launches (stream order), and cvt_k rewrites
  // the region at the start of every call, so the overlay is race-free.
  char* p = (char*)d_ws;
  char* regionA = p;        p += (size_t)12 * 1024 * 1024;
  u16*   w_x_b  = (u16*)p;  p += (size_t)196608 * 2;        // 384 KB
  u16*   w_dt_b = (u16*)p;  p += (size_t)131072 * 2;        // 256 KB
  u16*   w_out_b= (u16*)p;  p += (size_t)2097152 * 2;       // 4 MB
  u16*   xz     = (u16*)p;  p += (size_t)2048 * 4096 * 2;   // 16 MB
  u16*   xc     = (u16*)p;  p += (size_t)2048 * 2048 * 2;   // 8 MB (also y, in-place)
  u16*   xdbl   = (u16*)p;  p += (size_t)2048 * 96 * 2;     // 384 KB
  float* dtf    = (float*)p;                                // 16 MB

  u16*   hs_b   = (u16*)regionA;                            // 4 MB
  u16*   w_in_b = (u16*)(regionA + (size_t)2097152 * 2);    // 8 MB
  float* hseg   = (float*)regionA;                          // 8 MB  (S,B,2048,16)
  float* sdt    = (float*)(regionA + (size_t)SSEG * 65536 * 4);  // 0.5 MB
  float* out    = (float*)d_out;

  // convert f32 -> bf16 GEMM operands
  cvt_k<<<8512, 256, 0, stream>>>(hs, w_in, w_x, w_dt, w_out,
                                  hs_b, w_in_b, w_x_b, w_dt_b, w_out_b);
  // xz = hs @ in_proj_w^T            (2048 x 4096, K=1024)
  gemm_bt<0><<<dim3(16, 32), 256, 0, stream>>>(hs_b, 1024, w_in_b, 1024, xz, 4096, 2048, 4096, 1024, nullptr);
  // x = silu(causal_conv(x) + b)
  conv_silu_k<<<16384, 256, 0, stream>>>(xz, cw, cb, xc);
  // x_dbl = x @ x_proj_w^T           (2048 x 96, K=2048)
  gemm_bt<0><<<dim3(16, 1), 256, 0, stream>>>(xc, 2048, w_x_b, 2048, xdbl, 96, 2048, 96, 2048, nullptr);
  // dt = softplus(x_dbl[:, :64] @ dt_proj_w^T + b)   (2048 x 2048, K=64)
  gemm_bt<1><<<dim3(16, 16), 256, 0, stream>>>(xdbl, 96, w_dt_b, 64, dtf, 2048, 2048, 2048, 64, b_dt);
  // segmented selective scan (no LDS, no shuffles; state overlaid on region A)
  scan1_k<<<dim3(8, 2, SSEG), 256, 0, stream>>>(dtf, xdbl, xc, A_log, hseg, sdt);
  combine_k<<<256, 256, 0, stream>>>(hseg, sdt, A_log);
  scan3_k<<<dim3(8, 2, SSEG), 256, 0, stream>>>(dtf, xdbl, xc, xz, A_log, Dw, hseg);
  // out = y @ out_proj_w^T           (2048 x 1024, K=2048)
  gemm_bt<2><<<dim3(16, 8), 256, 0, stream>>>(xc, 2048, w_out_b, 2048, out, 1024, 2048, 1024, 2048, nullptr);
}

// Round 9
// 259.557 us; speedup vs baseline: 2.1292x; 1.1519x over previous
//
#include <hip/hip_runtime.h>

typedef unsigned short u16;
typedef unsigned int   u32;
typedef __attribute__((ext_vector_type(8))) short bf16x8;   // 8 bf16 in 4 VGPRs
typedef __attribute__((ext_vector_type(4))) float f32x4;

__device__ inline float bf2f(u16 u) { return __uint_as_float(((u32)u) << 16); }
__device__ inline u16 f2bf(float f) {
  u32 u = __float_as_uint(f);
  return (u16)((u + 0x7FFFu + ((u >> 16) & 1u)) >> 16);   // RNE
}

__device__ inline void gld_lds16(const u16* g, u16* l) {
  __builtin_amdgcn_global_load_lds((const __attribute__((address_space(1))) void*)g,
                                   (__attribute__((address_space(3))) void*)l,
                                   16, 0, 0);
}

// ---- f32 -> bf16 conversion of the 5 GEMM operand tensors (vec4) ----
__global__ __launch_bounds__(256) void cvt_k(
    const float* __restrict__ hs, const float* __restrict__ w_in,
    const float* __restrict__ w_x, const float* __restrict__ w_dt,
    const float* __restrict__ w_out,
    u16* __restrict__ hs_b, u16* __restrict__ w_in_b, u16* __restrict__ w_x_b,
    u16* __restrict__ w_dt_b, u16* __restrict__ w_out_b)
{
  u32 v = blockIdx.x * 256 + threadIdx.x;   // vec4 index, total 2179072
  const float* s; u16* d; u32 loc;
  if      (v < 524288u)  { s = hs;    d = hs_b;    loc = v; }
  else if (v < 1572864u) { s = w_in;  d = w_in_b;  loc = v - 524288u; }
  else if (v < 1622016u) { s = w_x;   d = w_x_b;   loc = v - 1572864u; }
  else if (v < 1654784u) { s = w_dt;  d = w_dt_b;  loc = v - 1622016u; }
  else                   { s = w_out; d = w_out_b; loc = v - 1654784u; }
  float4 f = ((const float4*)s)[loc];
  ushort4 o;
  o.x = f2bf(f.x); o.y = f2bf(f.y); o.z = f2bf(f.z); o.w = f2bf(f.w);
  ((ushort4*)d)[loc] = o;
}

// C = A (MxK bf16, lda) * B^T (B NxK bf16 row-major, ldb), 128x128 tile, BK=32.
// Klen = K handled per z-slice; block z covers k in [z*Klen, (z+1)*Klen).
// EPI==0: store bf16. EPI==1: f32 softplus(acc+bias[col]). EPI==2: f32.
// EPI==3: f32 partial at C + z*M*ldc (split-K).
template <int EPI>
__global__ __launch_bounds__(256) void gemm_bt(
    const u16* __restrict__ A, int lda,
    const u16* __restrict__ B, int ldb,
    void* __restrict__ C, int ldc,
    int M, int N, int Klen,
    const float* __restrict__ bias)
{
  __shared__ u16 sA[128 * 32];
  __shared__ u16 sB[128 * 32];
  const int tid  = threadIdx.x;
  const int wave = tid >> 6, lane = tid & 63;
  const int row0 = blockIdx.x * 128, col0 = blockIdx.y * 128;
  const int kbase = blockIdx.z * Klen;
  const int r  = lane >> 2, c8 = (lane & 3) * 8;
  const int wm = (wave >> 1) * 64, wn = (wave & 1) * 64;
  const int tm = lane & 15, quad = lane >> 4;

  f32x4 acc[4][4];
#pragma unroll
  for (int i = 0; i < 4; ++i)
#pragma unroll
    for (int j = 0; j < 4; ++j) acc[i][j] = f32x4{0.f, 0.f, 0.f, 0.f};

  for (int k0 = kbase; k0 < kbase + Klen; k0 += 32) {
    for (int s = wave; s < 8; s += 4) {
      const u16* ga = A + (size_t)(row0 + s * 16 + r) * lda + (k0 + c8);
      gld_lds16(ga, &sA[s * 512 + lane * 8]);
      int br = col0 + s * 16 + r; br = br < N ? br : N - 1;
      const u16* gb = B + (size_t)br * ldb + (k0 + c8);
      gld_lds16(gb, &sB[s * 512 + lane * 8]);
    }
    __syncthreads();
    bf16x8 af[4], bfv[4];
#pragma unroll
    for (int i = 0; i < 4; ++i) af[i]  = *(const bf16x8*)&sA[(wm + i * 16 + tm) * 32 + quad * 8];
#pragma unroll
    for (int j = 0; j < 4; ++j) bfv[j] = *(const bf16x8*)&sB[(wn + j * 16 + tm) * 32 + quad * 8];
#pragma unroll
    for (int i = 0; i < 4; ++i)
#pragma unroll
      for (int j = 0; j < 4; ++j)
        acc[i][j] = __builtin_amdgcn_mfma_f32_16x16x32_bf16(af[i], bfv[j], acc[i][j], 0, 0, 0);
    __syncthreads();
  }

  const size_t zoff = (size_t)blockIdx.z * M * ldc;   // split-K partial offset
#pragma unroll
  for (int j = 0; j < 4; ++j) {
    int col = col0 + wn + j * 16 + tm;
    if (col >= N) continue;
#pragma unroll
    for (int i = 0; i < 4; ++i) {
      int rb = row0 + wm + i * 16 + quad * 4;
      f32x4 v = acc[i][j];
#pragma unroll
      for (int t = 0; t < 4; ++t) {
        float f = v[t];
        size_t idx = (size_t)(rb + t) * ldc + col;
        if (EPI == 1) {
          f += bias[col];
          f = (f > 20.f) ? f : log1pf(__expf(f));
          ((float*)C)[idx] = f;
        } else if (EPI == 2) {
          ((float*)C)[idx] = f;
        } else if (EPI == 3) {
          ((float*)C)[zoff + idx] = f;
        } else {
          ((u16*)C)[idx] = f2bf(f);
        }
      }
    }
  }
}

// sum KS split-K partials (each `total` f32), vec4. OUTBF==1: bf16 out, else f32.
template <int OUTBF>
__global__ __launch_bounds__(256) void red_k(
    const float* __restrict__ part, void* __restrict__ out, int total, int KS)
{
  int i = blockIdx.x * 256 + threadIdx.x;   // vec4 index; grid sized exactly
  f32x4 a = ((const f32x4*)part)[i];
  for (int ks = 1; ks < KS; ++ks)
    a += ((const f32x4*)(part + (size_t)ks * total))[i];
  if (OUTBF) {
    ushort4 o; o.x = f2bf(a[0]); o.y = f2bf(a[1]); o.z = f2bf(a[2]); o.w = f2bf(a[3]);
    ((ushort4*)out)[i] = o;
  } else {
    ((f32x4*)out)[i] = a;
  }
}

// depthwise causal conv (K=4) + bias + silu. xz: (B*L) x 4096 bf16, x = cols 0..2047
__global__ __launch_bounds__(256) void conv_silu_k(
    const u16* __restrict__ xz, const float* __restrict__ cw,
    const float* __restrict__ cb, u16* __restrict__ xc)
{
  int gid = blockIdx.x * 256 + threadIdx.x;
  int d = gid & 2047;
  int row = gid >> 11;        // b*1024 + l
  int l = row & 1023;
  float acc = cb[d];
#pragma unroll
  for (int k = 0; k < 4; ++k) {
    int ll = l - 3 + k;
    if (ll >= 0)
      acc += bf2f(xz[(size_t)(row - 3 + k) * 4096 + d]) * cw[d * 4 + k];
  }
  float s = acc / (1.f + __expf(-acc));
  xc[(size_t)row * 2048 + d] = f2bf(s);
}

// ===== segmented selective scan, S=32 segments of T=32, thread = (b, d, seg) =====
#define SSEG 32
#define TSEG 32

// pass 1: local scan with h0=0; emit h_end per (s,b,d,n) and sum(dt) per (s,b,d)
__global__ __launch_bounds__(256) void scan1_k(
    const float* __restrict__ dtf,   // (B*L, 2048) f32 post-softplus
    const u16* __restrict__ xdbl,    // (B*L, 96) bf16: [dt_r|Bm|Cm]
    const u16* __restrict__ xc,      // (B*L, 2048) bf16
    const float* __restrict__ A_log, // (2048,16) f32
    float* __restrict__ hseg,        // (S,B,2048,16) h_end out
    float* __restrict__ sdt_o)       // (S,B,2048)   sum(dt) out
{
  const int L = 1024, DI = 2048;
  int d = blockIdx.x * 256 + threadIdx.x;
  int b = blockIdx.y, s = blockIdx.z;
  float cA[16], h[16];
#pragma unroll
  for (int n = 0; n < 16; ++n) { cA[n] = -__expf(A_log[d * 16 + n]); h[n] = 0.f; }
  float sdt = 0.f;
  size_t row = (size_t)b * L + s * TSEG;
  const float* pdt = dtf + row * DI + d;
  const u16*   px  = xc  + row * DI + d;
  const u16*   pB  = xdbl + row * 96 + 64;
  for (int t = 0; t < TSEG; ++t) {
    float dt = *pdt;
    float xv = bf2f(*px);
    bf16x8 Bv0 = *(const bf16x8*)(pB);
    bf16x8 Bv1 = *(const bf16x8*)(pB + 8);
    float dBu = dt * xv;
    sdt += dt;
#pragma unroll
    for (int n = 0; n < 16; ++n) {
      float dA = __expf(dt * cA[n]);
      float Bn = bf2f((u16)(n < 8 ? Bv0[n] : Bv1[n - 8]));
      h[n] = fmaf(dA, h[n], dBu * Bn);
    }
    pdt += DI; px += DI; pB += 96;
  }
  size_t o = (((size_t)s * 2 + b) * 2048 + d) * 16;
#pragma unroll
  for (int n = 0; n < 16; ++n) hseg[o + n] = h[n];
  sdt_o[((size_t)s * 2 + b) * 2048 + d] = sdt;
}

// pass 2: sequential combine over segments; hseg: h_end in -> h_start out (in place)
__global__ __launch_bounds__(256) void combine_k(
    float* hseg, const float* __restrict__ sdt,
    const float* __restrict__ A_log)
{
  int gid = blockIdx.x * 256 + threadIdx.x;   // b*32768 + d*16 + n, 65536 total
  int b = gid >> 15, d = (gid >> 4) & 2047, n = gid & 15;
  float cA = -__expf(A_log[d * 16 + n]);
  float carry = 0.f;
  for (int s = 0; s < SSEG; ++s) {
    size_t o = (size_t)s * 65536 + gid;
    float he = hseg[o];
    float P = __expf(cA * sdt[(size_t)s * 4096 + b * 2048 + d]);
    hseg[o] = carry;                 // becomes h_start
    carry = fmaf(P, carry, he);
  }
}

// pass 3: rescan with true h_start; fuse y = C.h + x*D, gate with silu(z); y -> xcy in place
__global__ __launch_bounds__(256) void scan3_k(
    const float* __restrict__ dtf,
    const u16* __restrict__ xdbl,
    u16* xcy,                        // x_conv in, y out (same element, same iteration)
    const u16* __restrict__ xz,     // z = cols 2048..4095, ROW STRIDE 4096
    const float* __restrict__ A_log,
    const float* __restrict__ Dw,
    const float* __restrict__ hstart)
{
  const int L = 1024, DI = 2048;
  int d = blockIdx.x * 256 + threadIdx.x;
  int b = blockIdx.y, s = blockIdx.z;
  float cA[16], h[16];
  size_t ho = (((size_t)s * 2 + b) * 2048 + d) * 16;
#pragma unroll
  for (int n = 0; n < 16; ++n) { cA[n] = -__expf(A_log[d * 16 + n]); h[n] = hstart[ho + n]; }
  float Dd = Dw[d];
  size_t row = (size_t)b * L + s * TSEG;
  const float* pdt = dtf + row * DI + d;
  u16*         px  = xcy + row * DI + d;
  const u16*   pz  = xz  + row * 4096 + 2048 + d;
  const u16*   pBC = xdbl + row * 96 + 64;
  for (int t = 0; t < TSEG; ++t) {
    float dt = *pdt;
    float xv = bf2f(*px);
    float zv = bf2f(*pz);
    bf16x8 Bv0 = *(const bf16x8*)(pBC);
    bf16x8 Bv1 = *(const bf16x8*)(pBC + 8);
    bf16x8 Cv0 = *(const bf16x8*)(pBC + 16);
    bf16x8 Cv1 = *(const bf16x8*)(pBC + 24);
    float dBu = dt * xv;
    float y = xv * Dd;
#pragma unroll
    for (int n = 0; n < 16; ++n) {
      float dA = __expf(dt * cA[n]);
      float Bn = bf2f((u16)(n < 8 ? Bv0[n] : Bv1[n - 8]));
      float Cn = bf2f((u16)(n < 8 ? Cv0[n] : Cv1[n - 8]));
      h[n] = fmaf(dA, h[n], dBu * Bn);
      y = fmaf(h[n], Cn, y);
    }
    float sig = 1.f / (1.f + __expf(-zv));
    *px = f2bf(y * (zv * sig));
    pdt += DI; px += DI; pz += 4096; pBC += 96;   // xz row stride is 4096
  }
}

extern "C" void kernel_launch(void* const* d_in, const int* in_sizes, int n_in,
                              void* d_out, int out_size, void* d_ws, size_t ws_size,
                              hipStream_t stream)
{
  const float* hs    = (const float*)d_in[0];   // (2,1024,1024)
  const float* w_in  = (const float*)d_in[1];   // (4096,1024)
  const float* cw    = (const float*)d_in[2];   // (2048,1,4)
  const float* cb    = (const float*)d_in[3];   // (2048,)
  const float* w_x   = (const float*)d_in[4];   // (96,2048)
  const float* w_dt  = (const float*)d_in[5];   // (2048,64)
  const float* b_dt  = (const float*)d_in[6];   // (2048,)
  const float* A_log = (const float*)d_in[7];   // (2048,16)
  const float* Dw    = (const float*)d_in[8];   // (2048,)
  const float* w_out = (const float*)d_in[9];   // (1024,2048)

  // Workspace ~106 MB (harness ws poison shows ws_size ≈ 268 MB).
  // Region A (first 12 MB) time-shared: phase 1 = hs_b + w_in_b (dead after
  // gemm1); phase 2 = hseg + sdt (scan state). Race-free by stream order.
  char* p = (char*)d_ws;
  char* regionA = p;        p += (size_t)12 * 1024 * 1024;
  u16*   w_x_b  = (u16*)p;  p += (size_t)196608 * 2;        // 384 KB
  u16*   w_dt_b = (u16*)p;  p += (size_t)131072 * 2;        // 256 KB
  u16*   w_out_b= (u16*)p;  p += (size_t)2097152 * 2;       // 4 MB
  u16*   xz     = (u16*)p;  p += (size_t)2048 * 4096 * 2;   // 16 MB
  u16*   xc     = (u16*)p;  p += (size_t)2048 * 2048 * 2;   // 8 MB (also y, in-place)
  u16*   xdbl   = (u16*)p;  p += (size_t)2048 * 96 * 2;     // 384 KB
  float* dtf    = (float*)p;p += (size_t)2048 * 2048 * 4;   // 16 MB
  float* pout   = (float*)p;p += (size_t)4 * 2048 * 1024 * 4;  // 33.5 MB split-K partials
  float* px     = (float*)p;                                   // 12.6 MB split-K partials

  u16*   hs_b   = (u16*)regionA;                            // 4 MB
  u16*   w_in_b = (u16*)(regionA + (size_t)2097152 * 2);    // 8 MB
  float* hseg   = (float*)regionA;                          // 8 MB  (S,B,2048,16)
  float* sdt    = (float*)(regionA + (size_t)SSEG * 65536 * 4);  // 0.5 MB
  float* out    = (float*)d_out;

  // convert f32 -> bf16 GEMM operands
  cvt_k<<<8512, 256, 0, stream>>>(hs, w_in, w_x, w_dt, w_out,
                                  hs_b, w_in_b, w_x_b, w_dt_b, w_out_b);
  // xz = hs @ in_proj_w^T            (2048 x 4096, K=1024)
  gemm_bt<0><<<dim3(16, 32, 1), 256, 0, stream>>>(hs_b, 1024, w_in_b, 1024, xz, 4096, 2048, 4096, 1024, nullptr);
  // x = silu(causal_conv(x) + b)
  conv_silu_k<<<16384, 256, 0, stream>>>(xz, cw, cb, xc);
  // x_dbl = x @ x_proj_w^T           (2048 x 96, K=2048) — split-K x16
  gemm_bt<3><<<dim3(16, 1, 16), 256, 0, stream>>>(xc, 2048, w_x_b, 2048, px, 96, 2048, 96, 128, nullptr);
  red_k<1><<<192, 256, 0, stream>>>(px, xdbl, 196608, 16);
  // dt = softplus(x_dbl[:, :64] @ dt_proj_w^T + b)   (2048 x 2048, K=64)
  gemm_bt<1><<<dim3(16, 16, 1), 256, 0, stream>>>(xdbl, 96, w_dt_b, 64, dtf, 2048, 2048, 2048, 64, b_dt);
  // segmented selective scan (no LDS, no shuffles; state overlaid on region A)
  scan1_k<<<dim3(8, 2, SSEG), 256, 0, stream>>>(dtf, xdbl, xc, A_log, hseg, sdt);
  combine_k<<<256, 256, 0, stream>>>(hseg, sdt, A_log);
  scan3_k<<<dim3(8, 2, SSEG), 256, 0, stream>>>(dtf, xdbl, xc, xz, A_log, Dw, hseg);
  // out = y @ out_proj_w^T           (2048 x 1024, K=2048) — split-K x4
  gemm_bt<3><<<dim3(16, 8, 4), 256, 0, stream>>>(xc, 2048, w_out_b, 2048, pout, 1024, 2048, 1024, 512, nullptr);
  red_k<0><<<2048, 256, 0, stream>>>(pout, out, 2097152, 4);
}